// Round 13
// baseline (61.465 us; speedup 1.0000x reference)
//
#include <hip/hip_runtime.h>
#include <hip/hip_bf16.h>

// Problem: B=4096, D_IN=D_H=K=1024.
//   x = input_ @ fq(Wi,4).T + bi ; h = hidden @ fq(Wr,4).T + br
//   out = tanh(LN(x) + LN(h))
// ws layout:
//   +0      : bmax f32[512] (per-block weight absmax; 0..255 Wi, 256..511 Wr)
//   +2048   : scales f32[2]
//   +4096   : Qi bf16 ints, 2 MB
//   +2M+4096: Qr bf16 ints, 2 MB
//   +4M+4096: Xq bf16 (x pre-LN, unscaled), 8 MB
//   +12M+..: Hq bf16 (h pre-LN, unscaled), 8 MB

typedef float  f32x4  __attribute__((ext_vector_type(4)));
typedef __bf16 bf16x8 __attribute__((ext_vector_type(8)));
typedef __bf16 bf16x4 __attribute__((ext_vector_type(4)));

#define KDIM 1024

// ---------------- weight absmax (per-block partial max) ----------------
__global__ __launch_bounds__(256)
void absmax_k(const float* __restrict__ Wi, const float* __restrict__ Wr,
              float* __restrict__ bmax)
{
    const int b = blockIdx.x, t = threadIdx.x;
    const int tensor = b >> 8;
    const float* W = tensor ? Wr : Wi;
    const int lane = t & 63, wid = t >> 6;
    const f32x4* p = (const f32x4*)W;
    const size_t base = (size_t)(b & 255) * 1024;
    float m = 0.f;
#pragma unroll
    for (int k = 0; k < 4; ++k) {
        f32x4 v = p[base + k * 256 + t];
        m = fmaxf(m, fmaxf(fmaxf(fabsf(v[0]), fabsf(v[1])),
                           fmaxf(fabsf(v[2]), fabsf(v[3]))));
    }
#pragma unroll
    for (int o = 32; o >= 1; o >>= 1) m = fmaxf(m, __shfl_xor(m, o));
    __shared__ float wm_[4];
    if (lane == 0) wm_[wid] = m;
    __syncthreads();
    if (t == 0) bmax[b] = fmaxf(fmaxf(wm_[0], wm_[1]), fmaxf(wm_[2], wm_[3]));
}

// ---------------- quantize weights to integer bf16 (reduces bmax per block) ----------------
__global__ __launch_bounds__(256)
void quant_k(const float* __restrict__ Wi, const float* __restrict__ Wr,
             const float* __restrict__ bmax, float* __restrict__ scales,
             __bf16* __restrict__ Qi, __bf16* __restrict__ Qr)
{
    const int tensor = blockIdx.x >> 8;
    const int b = blockIdx.x & 255;
    const int t = threadIdx.x;
    const int lane = t & 63, wid = t >> 6;

    float m = bmax[tensor * 256 + t];
#pragma unroll
    for (int o = 32; o >= 1; o >>= 1) m = fmaxf(m, __shfl_xor(m, o));
    __shared__ float wm_[4];
    if (lane == 0) wm_[wid] = m;
    __syncthreads();
    m = fmaxf(fmaxf(wm_[0], wm_[1]), fmaxf(wm_[2], wm_[3]));
    const float s = m / 7.0f;
    if (t == 0 && b == 0) scales[tensor] = s;

    const float* W = tensor ? Wr : Wi;
    __bf16* Q = tensor ? Qr : Qi;
#pragma unroll
    for (int j = 0; j < 2; ++j) {
        const int e = b * 4096 + (j * 256 + t) * 8;
        f32x4 v0 = ((const f32x4*)(W + e))[0];
        f32x4 v1 = ((const f32x4*)(W + e))[1];
        bf16x8 o;
#pragma unroll
        for (int i = 0; i < 4; ++i) {
            o[i]     = (__bf16)rintf(v0[i] / s);
            o[i + 4] = (__bf16)rintf(v1[i] / s);
        }
        *(bf16x8*)(Q + e) = o;
    }
}

// ---------------- dual MFMA GEMM, f32-A direct: 128x128, 8 waves (2Mx4N) ----------------
// A: f32 straight from the input (NO pre-conversion pass), staged via
//    global_load_lds into 2 LDS buffers (32 KB each); fragments read as
//    2x ds_read_b128 (f32x4 pairs) and converted to bf16 in-register (RNE,
//    same bytes as the old prep pass => bit-identical output).
//    A chunk swizzle: LDS chunk (row, ci) holds global chunk gc = ci^(row&15)
//    -> frag reads hit 16 distinct slots across 16 rows = 2-way = free.
// B: quantized bf16 via DMA, 2 buffers (16 KB each). LDS total 96 KB.
// Distance-1 staging, 1 barrier/iter. Ordered read groups with counted lgkm:
//   [STAGE(kt+1)] [grp0: B-kk0(2)+A-kk0(8)] [grp1: B-kk1(2)+A-kk1(8)]
//   lgkm(10) -> grp0 done -> cvt -> 8 MFMA kk0
//   lgkm(0)  -> grp1 done -> cvt -> vmcnt(0) -> barrier -> 8 MFMA kk1
// Overwrite safety: reads of buf[bk^1] (iter kt-1) retired at that iter's
// lgkm(0) BEFORE its barrier; STAGE(kt+1) into buf[bk^1] is after it.
__global__ __launch_bounds__(512, 1)
void gemm_f32(const float* __restrict__ A0, const float* __restrict__ A1,
              const __bf16* __restrict__ W0, const __bf16* __restrict__ W1,
              __bf16* __restrict__ C0, __bf16* __restrict__ C1)
{
    __shared__ f32x4  ldsA[2][2048];   // 2 x 32 KB: 128 rows x 16 chunks(f32x4)
    __shared__ bf16x8 ldsB[2][1024];   // 2 x 16 KB: 128 rows x 8 chunks(bf16x8)

    // XCD-aware bijective swizzle (512 blocks, 8 XCDs)
    const int b = blockIdx.x;
    const int swz = (b & 7) * 64 + (b >> 3);
    const int which = swz >> 8;
    const int r = swz & 255;
    const int bm = r >> 3, bn = r & 7;   // bm 0..31 (M/128), bn 0..7 (N/128)

    const float*  A = which ? A1 : A0;
    const __bf16* W = which ? W1 : W0;
    __bf16*       C = which ? C1 : C0;

    const int t = threadIdx.x;
    const int l = t & 63, w = t >> 6;
    const int wm = w >> 2, wn = w & 3;   // wave grid 2M x 4N, per-wave 64x32
    const int l15 = l & 15, l7 = l & 7, lq = l >> 4;

    const float*  gA = A + (size_t)(bm * 128) * KDIM;
    const __bf16* gB = W + (size_t)(bn * 128) * KDIM;

    // A staging: 2048 chunks/buf; thread t stages c = j*512+t.
    // LDS chunk (row, ci) <- global chunk gc = ci ^ (row&15)
    int srcA[4];
#pragma unroll
    for (int j = 0; j < 4; ++j) {
        const int c = j * 512 + t;
        const int row = c >> 4, ci = c & 15;
        srcA[j] = row * KDIM + ((ci ^ (row & 15)) << 2);   // f32 elements
    }
    // B staging (unchanged proven involution at bf16x8 granularity)
    int srcB[2];
#pragma unroll
    for (int j = 0; j < 2; ++j) {
        const int c = j * 512 + t;
        const int row = c >> 3, g = (c & 7) ^ (row & 7);
        srcB[j] = row * KDIM + g * 8;                      // bf16 elements
    }

#define STAGE(bb, kt)                                                          \
    do {                                                                       \
        _Pragma("unroll")                                                      \
        for (int j = 0; j < 4; ++j)                                            \
            __builtin_amdgcn_global_load_lds(                                  \
                (const __attribute__((address_space(1))) unsigned*)(gA + srcA[j] + (kt) * 64), \
                (__attribute__((address_space(3))) unsigned*)(&ldsA[bb][(j) * 512 + t]), \
                16, 0, 0);                                                     \
        _Pragma("unroll")                                                      \
        for (int j = 0; j < 2; ++j)                                            \
            __builtin_amdgcn_global_load_lds(                                  \
                (const __attribute__((address_space(1))) unsigned*)(gB + srcB[j] + (kt) * 64), \
                (__attribute__((address_space(3))) unsigned*)(&ldsB[bb][(j) * 512 + t]), \
                16, 0, 0);                                                     \
    } while (0)

    // fragment LDS offsets: A chunk = row*16 + ((kq*2) ^ (row&15)); pair at ^1
    int offA[2][4], offB[2][2];
#pragma unroll
    for (int kk = 0; kk < 2; ++kk) {
        const int kq = kk * 4 + lq;
#pragma unroll
        for (int mi = 0; mi < 4; ++mi) {
            const int row = wm * 64 + mi * 16 + l15;
            offA[kk][mi] = row * 16 + ((kq * 2) ^ (row & 15));
        }
#pragma unroll
        for (int ni = 0; ni < 2; ++ni) {
            const int row = wn * 32 + ni * 16 + l15;
            offB[kk][ni] = row * 8 + (kq ^ (row & 7));
        }
    }

    f32x4 acc[4][2];
#pragma unroll
    for (int mi = 0; mi < 4; ++mi)
#pragma unroll
        for (int ni = 0; ni < 2; ++ni) acc[mi][ni] = (f32x4){0.f, 0.f, 0.f, 0.f};

#define LGKM(n)                                                                \
    do { asm volatile("s_waitcnt lgkmcnt(" #n ")" ::: "memory");               \
         __builtin_amdgcn_sched_barrier(0); } while (0)

    // prologue: stage kt=0 -> buf0, drain
    STAGE(0, 0);
    asm volatile("s_waitcnt vmcnt(0)" ::: "memory");
    __builtin_amdgcn_s_barrier();

#pragma unroll
    for (int kt = 0; kt < 16; ++kt) {
        const int bk = kt & 1;
        const f32x4*  LAf = &ldsA[bk][0];
        const bf16x8* LB  = &ldsB[bk][0];

        if (kt < 15) STAGE(bk ^ 1, kt + 1);     // 6 vmem ops

        // ordered read groups (lgkm in-order retirement)
        bf16x8 bfv0[2], bfv1[2];
        f32x4 a0[4][2], a1[4][2];
#pragma unroll
        for (int ni = 0; ni < 2; ++ni) bfv0[ni] = LB[offB[0][ni]];
#pragma unroll
        for (int mi = 0; mi < 4; ++mi) {
            a0[mi][0] = LAf[offA[0][mi]];
            a0[mi][1] = LAf[offA[0][mi] ^ 1];
        }
        __builtin_amdgcn_sched_barrier(0);
#pragma unroll
        for (int ni = 0; ni < 2; ++ni) bfv1[ni] = LB[offB[1][ni]];
#pragma unroll
        for (int mi = 0; mi < 4; ++mi) {
            a1[mi][0] = LAf[offA[1][mi]];
            a1[mi][1] = LAf[offA[1][mi] ^ 1];
        }
        __builtin_amdgcn_sched_barrier(0);

        LGKM(10);                               // group0 (B-kk0 + A-kk0) landed
        bf16x8 af0[4];
#pragma unroll
        for (int mi = 0; mi < 4; ++mi) {
            bf16x8 v;
#pragma unroll
            for (int i = 0; i < 4; ++i) {
                v[i]     = (__bf16)a0[mi][0][i];
                v[i + 4] = (__bf16)a0[mi][1][i];
            }
            af0[mi] = v;
        }
        __builtin_amdgcn_s_setprio(1);
#pragma unroll
        for (int mi = 0; mi < 4; ++mi)
#pragma unroll
            for (int ni = 0; ni < 2; ++ni)
                acc[mi][ni] = __builtin_amdgcn_mfma_f32_16x16x32_bf16(
                    bfv0[ni], af0[mi], acc[mi][ni], 0, 0, 0);
        __builtin_amdgcn_s_setprio(0);

        LGKM(0);                                // group1 landed; all reads retired
        bf16x8 af1[4];
#pragma unroll
        for (int mi = 0; mi < 4; ++mi) {
            bf16x8 v;
#pragma unroll
            for (int i = 0; i < 4; ++i) {
                v[i]     = (__bf16)a1[mi][0][i];
                v[i + 4] = (__bf16)a1[mi][1][i];
            }
            af1[mi] = v;
        }

        if (kt < 15) {
            asm volatile("s_waitcnt vmcnt(0)" ::: "memory");   // buf kt+1 staged
            __builtin_amdgcn_sched_barrier(0);
            __builtin_amdgcn_s_barrier();
        }

        __builtin_amdgcn_s_setprio(1);
#pragma unroll
        for (int mi = 0; mi < 4; ++mi)
#pragma unroll
            for (int ni = 0; ni < 2; ++ni)
                acc[mi][ni] = __builtin_amdgcn_mfma_f32_16x16x32_bf16(
                    bfv1[ni], af1[mi], acc[mi][ni], 0, 0, 0);
        __builtin_amdgcn_s_setprio(0);
    }

    // C write (swapped-operand layout): batch = lane&15 (+mi*16),
    // feat = (lane>>4)*4 + rr (+ni*16); one 8B bf16x4 store per fragment
    const int batch0 = bm * 128 + wm * 64 + l15;
    const int feat0  = bn * 128 + wn * 32 + (lq << 2);
#pragma unroll
    for (int mi = 0; mi < 4; ++mi)
#pragma unroll
        for (int ni = 0; ni < 2; ++ni) {
            bf16x4 o;
#pragma unroll
            for (int rr = 0; rr < 4; ++rr) o[rr] = (__bf16)acc[mi][ni][rr];
            *(bf16x4*)(C + (size_t)(batch0 + mi * 16) * KDIM + feat0 + ni * 16) = o;
        }
#undef STAGE
#undef LGKM
}

// ---------------- fused scale+bias, LN(x), LN(h), tanh — one row per WAVE ----------------
__global__ __launch_bounds__(256)
void ln_tanh_k(const __bf16* __restrict__ X, const __bf16* __restrict__ Hh,
               const float* __restrict__ bi, const float* __restrict__ br,
               const float* __restrict__ scales, float* __restrict__ out)
{
    const int t = threadIdx.x;
    const int lane = t & 63, wid = t >> 6;
    const int row = blockIdx.x * 4 + wid;
    const float si = scales[0];
    const float sr = scales[1];

    const bf16x8* xp = (const bf16x8*)(X  + (size_t)row * 1024 + lane * 16);
    const bf16x8* hp = (const bf16x8*)(Hh + (size_t)row * 1024 + lane * 16);
    bf16x8 xv0 = xp[0], xv1 = xp[1];
    bf16x8 hv0 = hp[0], hv1 = hp[1];

    float xs[16], hs[16];
    float sx = 0.f, sh = 0.f;
#pragma unroll
    for (int q = 0; q < 4; ++q) {
        f32x4 bviq = ((const f32x4*)bi)[lane * 4 + q];
        f32x4 bvrq = ((const f32x4*)br)[lane * 4 + q];
#pragma unroll
        for (int j = 0; j < 4; ++j) {
            const int e = q * 4 + j;
            const float xf = (e < 8) ? (float)xv0[e] : (float)xv1[e - 8];
            const float hf = (e < 8) ? (float)hv0[e] : (float)hv1[e - 8];
            xs[e] = xf * si + bviq[j];
            hs[e] = hf * sr + bvrq[j];
            sx += xs[e]; sh += hs[e];
        }
    }

#pragma unroll
    for (int o = 32; o >= 1; o >>= 1) { sx += __shfl_xor(sx, o); sh += __shfl_xor(sh, o); }
    const float mx = sx * (1.0f / 1024.0f), mh = sh * (1.0f / 1024.0f);

    float vx = 0.f, vh = 0.f;
#pragma unroll
    for (int e = 0; e < 16; ++e) {
        xs[e] -= mx; hs[e] -= mh;
        vx += xs[e] * xs[e]; vh += hs[e] * hs[e];
    }
#pragma unroll
    for (int o = 32; o >= 1; o >>= 1) { vx += __shfl_xor(vx, o); vh += __shfl_xor(vh, o); }
    const float rsx = rsqrtf(vx * (1.0f / 1024.0f) + 1e-5f);
    const float rsh = rsqrtf(vh * (1.0f / 1024.0f) + 1e-5f);

    float* op = out + (size_t)row * 1024 + lane * 16;
#pragma unroll
    for (int q = 0; q < 4; ++q) {
        f32x4 o4;
#pragma unroll
        for (int j = 0; j < 4; ++j) {
            const int e = q * 4 + j;
            o4[j] = tanhf(xs[e] * rsx + hs[e] * rsh);
        }
        ((f32x4*)op)[q] = o4;
    }
}

extern "C" void kernel_launch(void* const* d_in, const int* in_sizes, int n_in,
                              void* d_out, int out_size, void* d_ws, size_t ws_size,
                              hipStream_t stream)
{
    const float* input_ = (const float*)d_in[0];
    const float* hidden = (const float*)d_in[1];
    const float* Wi     = (const float*)d_in[2];
    const float* bi     = (const float*)d_in[3];
    const float* Wr     = (const float*)d_in[4];
    const float* br     = (const float*)d_in[5];
    float* out = (float*)d_out;

    char* ws = (char*)d_ws;
    float* bmax   = (float*)ws;
    float* scales = (float*)(ws + 2048);
    __bf16* Qi = (__bf16*)(ws + 4096);
    __bf16* Qr = (__bf16*)(ws + 4096 + (1u << 21));
    __bf16* Xq = (__bf16*)(ws + 4096 + (2u << 21));
    __bf16* Hq = (__bf16*)(ws + 4096 + (2u << 21) + (1u << 23));

    absmax_k<<<512, 256, 0, stream>>>(Wi, Wr, bmax);
    quant_k<<<512, 256, 0, stream>>>(Wi, Wr, bmax, scales, Qi, Qr);
    gemm_f32<<<512, 512, 0, stream>>>(input_, hidden, Qi, Qr, Xq, Hq);
    ln_tanh_k<<<1024, 256, 0, stream>>>(Xq, Hq, bi, br, scales, out);
}

// Round 14
// 47.561 us; speedup vs baseline: 1.2923x; 1.2923x over previous
//
#include <hip/hip_runtime.h>
#include <hip/hip_bf16.h>

// Problem: B=4096, D_IN=D_H=K=1024.
//   x = input_ @ fq(Wi,4).T + bi ; h = hidden @ fq(Wr,4).T + br
//   out = tanh(LN(x) + LN(h))
// ws layout:
//   +0      : bmax f32[512]
//   +2048   : scales f32[2]
//   +4096   : Qi bf16 ints, 2 MB
//   +2M+4096: Qr bf16 ints, 2 MB
//   +4M+4096: Abf bf16, 8 MB
//   +12M+..: Hbf bf16, 8 MB
//   +20M+..: Xq bf16, 8 MB
//   +28M+..: Hq bf16, 8 MB

typedef float  f32x4  __attribute__((ext_vector_type(4)));
typedef __bf16 bf16x8 __attribute__((ext_vector_type(8)));
typedef __bf16 bf16x4 __attribute__((ext_vector_type(4)));

#define KDIM 1024

// ---------------- fused: weight absmax (blocks 0..511) + activation cvt (512..2559) ----------------
__global__ __launch_bounds__(256)
void prep1_k(const float* __restrict__ A, const float* __restrict__ Hh,
             const float* __restrict__ Wi, const float* __restrict__ Wr,
             float* __restrict__ bmax,
             __bf16* __restrict__ Abf, __bf16* __restrict__ Hbf)
{
    const int b = blockIdx.x, t = threadIdx.x;
    if (b < 512) {
        const int tensor = b >> 8;
        const float* W = tensor ? Wr : Wi;
        const int lane = t & 63, wid = t >> 6;
        const f32x4* p = (const f32x4*)W;
        const size_t base = (size_t)(b & 255) * 1024;
        float m = 0.f;
#pragma unroll
        for (int k = 0; k < 4; ++k) {
            f32x4 v = p[base + k * 256 + t];
            m = fmaxf(m, fmaxf(fmaxf(fabsf(v[0]), fabsf(v[1])),
                               fmaxf(fabsf(v[2]), fabsf(v[3]))));
        }
#pragma unroll
        for (int o = 32; o >= 1; o >>= 1) m = fmaxf(m, __shfl_xor(m, o));
        __shared__ float wm_[4];
        if (lane == 0) wm_[wid] = m;
        __syncthreads();
        if (t == 0) bmax[b] = fmaxf(fmaxf(wm_[0], wm_[1]), fmaxf(wm_[2], wm_[3]));
        return;
    }
    const int c = b - 512;
    const float* src = (c < 1024) ? A : Hh;
    __bf16* dst = (c < 1024) ? Abf : Hbf;
    const int base = (c & 1023) * 4096;
#pragma unroll
    for (int j = 0; j < 2; ++j) {
        const int e = base + (j * 256 + t) * 8;
        f32x4 v0 = ((const f32x4*)(src + e))[0];
        f32x4 v1 = ((const f32x4*)(src + e))[1];
        bf16x8 o;
#pragma unroll
        for (int i = 0; i < 4; ++i) {
            o[i]     = (__bf16)v0[i];
            o[i + 4] = (__bf16)v1[i];
        }
        *(bf16x8*)(dst + e) = o;
    }
}

// ---------------- quantize weights to integer bf16 ----------------
__global__ __launch_bounds__(256)
void quant_k(const float* __restrict__ Wi, const float* __restrict__ Wr,
             const float* __restrict__ bmax, float* __restrict__ scales,
             __bf16* __restrict__ Qi, __bf16* __restrict__ Qr)
{
    const int tensor = blockIdx.x >> 8;
    const int b = blockIdx.x & 255;
    const int t = threadIdx.x;
    const int lane = t & 63, wid = t >> 6;

    float m = bmax[tensor * 256 + t];
#pragma unroll
    for (int o = 32; o >= 1; o >>= 1) m = fmaxf(m, __shfl_xor(m, o));
    __shared__ float wm_[4];
    if (lane == 0) wm_[wid] = m;
    __syncthreads();
    m = fmaxf(fmaxf(wm_[0], wm_[1]), fmaxf(wm_[2], wm_[3]));
    const float s = m / 7.0f;
    if (t == 0 && b == 0) scales[tensor] = s;

    const float* W = tensor ? Wr : Wi;
    __bf16* Q = tensor ? Qr : Qi;
#pragma unroll
    for (int j = 0; j < 2; ++j) {
        const int e = b * 4096 + (j * 256 + t) * 8;
        f32x4 v0 = ((const f32x4*)(W + e))[0];
        f32x4 v1 = ((const f32x4*)(W + e))[1];
        bf16x8 o;
#pragma unroll
        for (int i = 0; i < 4; ++i) {
            o[i]     = (__bf16)rintf(v0[i] / s);
            o[i + 4] = (__bf16)rintf(v1[i] / s);
        }
        *(bf16x8*)(Q + e) = o;
    }
}

// ---------------- dual bf16 MFMA GEMM: 128x128 tile, 4 waves, 2 BLOCKS/CU ----------------
// The one untested combination: round-11's tuned inner loop (grouped reads,
// counted lgkm, single barrier) at 128^2 with 2-buf LDS = 64 KB exactly ->
// grid 512 = 2.0 blocks/CU (8 waves/CU). Within-block drains (vmcnt(0) +
// barrier, distance-1 staging) are covered by the SIBLING block's MFMAs
// (m114/m97 inter-block overlap — lost since round 4's 1-block/CU configs).
// Per iter: [reads(cur): grp0|grp1 ordered] [STAGE(cur^1, kt+1): 8 gll]
//   lgkm(8) -> grp0 landed -> 16 MFMA kk0
//   lgkm(0) -> grp1 landed -> 16 MFMA kk1
//   vmcnt(0) -> barrier
// Overwrite safety: cur^1's reads retired at PREVIOUS iter's lgkm(0), one
// barrier before this iter's STAGE touches it. Fragment bytes, swizzle and
// K-order identical to rounds 5-12 => bit-identical output.
__global__ __launch_bounds__(256, 2)
void gemm_dual(const __bf16* __restrict__ A0, const __bf16* __restrict__ A1,
               const __bf16* __restrict__ W0, const __bf16* __restrict__ W1,
               __bf16* __restrict__ C0, __bf16* __restrict__ C1)
{
    __shared__ bf16x8 lds[2][2048];   // [buf][A:0..1023 | B:1024..2047] = 64 KB

    // XCD-aware bijective swizzle (512 blocks, 8 XCDs)
    const int b = blockIdx.x;
    const int swz = (b & 7) * 64 + (b >> 3);
    const int which = swz >> 8;
    const int r = swz & 255;
    const int bm = r >> 3, bn = r & 7;   // bm 0..31 (M/128), bn 0..7 (N/128)

    const __bf16* A = which ? A1 : A0;
    const __bf16* W = which ? W1 : W0;
    __bf16*       C = which ? C1 : C0;

    const int t = threadIdx.x;
    const int l = t & 63, w = t >> 6;
    const int wm = w >> 1, wn = w & 1;   // wave grid 2M x 2N, per-wave 64x64
    const int l15 = l & 15, l7 = l & 7, lq = l >> 4;

    const __bf16* gA = A + (size_t)(bm * 128) * KDIM;
    const __bf16* gB = W + (size_t)(bn * 128) * KDIM;

    // staging source offsets (element units), pre-swizzled for linear LDS
    int srcA[4], srcB[4];
#pragma unroll
    for (int j = 0; j < 4; ++j) {
        const int c = j * 256 + t;       // chunk 0..1023 (row = c>>3)
        const int row = c >> 3, g = (c & 7) ^ (row & 7);
        srcA[j] = row * KDIM + g * 8;
        srcB[j] = row * KDIM + g * 8;
    }

#define STAGE(bb, kt)                                                          \
    do {                                                                       \
        _Pragma("unroll")                                                      \
        for (int j = 0; j < 4; ++j)                                            \
            __builtin_amdgcn_global_load_lds(                                  \
                (const __attribute__((address_space(1))) unsigned*)(gA + srcA[j] + (kt) * 64), \
                (__attribute__((address_space(3))) unsigned*)(&lds[bb][(j) * 256 + t]), \
                16, 0, 0);                                                     \
        _Pragma("unroll")                                                      \
        for (int j = 0; j < 4; ++j)                                            \
            __builtin_amdgcn_global_load_lds(                                  \
                (const __attribute__((address_space(1))) unsigned*)(gB + srcB[j] + (kt) * 64), \
                (__attribute__((address_space(3))) unsigned*)(&lds[bb][1024 + (j) * 256 + t]), \
                16, 0, 0);                                                     \
    } while (0)

    // fragment LDS chunk offsets [kk][idx]
    int offA[2][4], offB[2][4];
#pragma unroll
    for (int kk = 0; kk < 2; ++kk) {
        const int kq = kk * 4 + lq;
#pragma unroll
        for (int mi = 0; mi < 4; ++mi)
            offA[kk][mi] = (wm * 64 + mi * 16 + l15) * 8 + (kq ^ l7);
#pragma unroll
        for (int ni = 0; ni < 4; ++ni)
            offB[kk][ni] = (wn * 64 + ni * 16 + l15) * 8 + (kq ^ l7);
    }

    f32x4 acc[4][4];
#pragma unroll
    for (int mi = 0; mi < 4; ++mi)
#pragma unroll
        for (int ni = 0; ni < 4; ++ni) acc[mi][ni] = (f32x4){0.f, 0.f, 0.f, 0.f};

#define LGKM(n)                                                                \
    do { asm volatile("s_waitcnt lgkmcnt(" #n ")" ::: "memory");               \
         __builtin_amdgcn_sched_barrier(0); } while (0)

    // prologue: stage kt=0 -> buf0, drain, barrier
    STAGE(0, 0);
    asm volatile("s_waitcnt vmcnt(0)" ::: "memory");
    __builtin_amdgcn_s_barrier();

#pragma unroll
    for (int kt = 0; kt < 16; ++kt) {
        const int bk = kt & 1;
        const bf16x8* LA = &lds[bk][0];
        const bf16x8* LB = &lds[bk][1024];

        // ordered read groups (lgkm in-order retirement): grp0 = kk0, grp1 = kk1
        bf16x8 af[2][4], bfv[2][4];
#pragma unroll
        for (int ni = 0; ni < 4; ++ni) bfv[0][ni] = LB[offB[0][ni]];
#pragma unroll
        for (int mi = 0; mi < 4; ++mi) af[0][mi]  = LA[offA[0][mi]];
        __builtin_amdgcn_sched_barrier(0);
#pragma unroll
        for (int ni = 0; ni < 4; ++ni) bfv[1][ni] = LB[offB[1][ni]];
#pragma unroll
        for (int mi = 0; mi < 4; ++mi) af[1][mi]  = LA[offA[1][mi]];
        __builtin_amdgcn_sched_barrier(0);

        if (kt < 15) STAGE(bk ^ 1, kt + 1);   // 8 vmem ops into the other buf

        LGKM(8);                 // grp0 landed
        __builtin_amdgcn_s_setprio(1);
#pragma unroll
        for (int mi = 0; mi < 4; ++mi)
#pragma unroll
            for (int ni = 0; ni < 4; ++ni)
                acc[mi][ni] = __builtin_amdgcn_mfma_f32_16x16x32_bf16(
                    bfv[0][ni], af[0][mi], acc[mi][ni], 0, 0, 0);
        __builtin_amdgcn_s_setprio(0);

        LGKM(0);                 // grp1 landed; all reads of buf bk retired
        __builtin_amdgcn_s_setprio(1);
#pragma unroll
        for (int mi = 0; mi < 4; ++mi)
#pragma unroll
            for (int ni = 0; ni < 4; ++ni)
                acc[mi][ni] = __builtin_amdgcn_mfma_f32_16x16x32_bf16(
                    bfv[1][ni], af[1][mi], acc[mi][ni], 0, 0, 0);
        __builtin_amdgcn_s_setprio(0);

        if (kt < 15) {
            asm volatile("s_waitcnt vmcnt(0)" ::: "memory");   // buf kt+1 staged
            __builtin_amdgcn_sched_barrier(0);
            __builtin_amdgcn_s_barrier();     // drain covered by sibling block
        }
    }

    // C write (swapped-operand layout): batch = lane&15 (+mi*16),
    // feat = (lane>>4)*4 + rr (+ni*16); one 8B bf16x4 store per fragment
    const int batch0 = bm * 128 + wm * 64 + l15;
    const int feat0  = bn * 128 + wn * 64 + (lq << 2);
#pragma unroll
    for (int mi = 0; mi < 4; ++mi)
#pragma unroll
        for (int ni = 0; ni < 4; ++ni) {
            bf16x4 o;
#pragma unroll
            for (int rr = 0; rr < 4; ++rr) o[rr] = (__bf16)acc[mi][ni][rr];
            *(bf16x4*)(C + (size_t)(batch0 + mi * 16) * KDIM + feat0 + ni * 16) = o;
        }
#undef STAGE
#undef LGKM
}

// ---------------- fused scale+bias, LN(x), LN(h), tanh — one row per WAVE ----------------
__global__ __launch_bounds__(256)
void ln_tanh_k(const __bf16* __restrict__ X, const __bf16* __restrict__ Hh,
               const float* __restrict__ bi, const float* __restrict__ br,
               const float* __restrict__ scales, float* __restrict__ out)
{
    const int t = threadIdx.x;
    const int lane = t & 63, wid = t >> 6;
    const int row = blockIdx.x * 4 + wid;
    const float si = scales[0];
    const float sr = scales[1];

    const bf16x8* xp = (const bf16x8*)(X  + (size_t)row * 1024 + lane * 16);
    const bf16x8* hp = (const bf16x8*)(Hh + (size_t)row * 1024 + lane * 16);
    bf16x8 xv0 = xp[0], xv1 = xp[1];
    bf16x8 hv0 = hp[0], hv1 = hp[1];

    float xs[16], hs[16];
    float sx = 0.f, sh = 0.f;
#pragma unroll
    for (int q = 0; q < 4; ++q) {
        f32x4 bviq = ((const f32x4*)bi)[lane * 4 + q];
        f32x4 bvrq = ((const f32x4*)br)[lane * 4 + q];
#pragma unroll
        for (int j = 0; j < 4; ++j) {
            const int e = q * 4 + j;
            const float xf = (e < 8) ? (float)xv0[e] : (float)xv1[e - 8];
            const float hf = (e < 8) ? (float)hv0[e] : (float)hv1[e - 8];
            xs[e] = xf * si + bviq[j];
            hs[e] = hf * sr + bvrq[j];
            sx += xs[e]; sh += hs[e];
        }
    }

#pragma unroll
    for (int o = 32; o >= 1; o >>= 1) { sx += __shfl_xor(sx, o); sh += __shfl_xor(sh, o); }
    const float mx = sx * (1.0f / 1024.0f), mh = sh * (1.0f / 1024.0f);

    float vx = 0.f, vh = 0.f;
#pragma unroll
    for (int e = 0; e < 16; ++e) {
        xs[e] -= mx; hs[e] -= mh;
        vx += xs[e] * xs[e]; vh += hs[e] * hs[e];
    }
#pragma unroll
    for (int o = 32; o >= 1; o >>= 1) { vx += __shfl_xor(vx, o); vh += __shfl_xor(vh, o); }
    const float rsx = rsqrtf(vx * (1.0f / 1024.0f) + 1e-5f);
    const float rsh = rsqrtf(vh * (1.0f / 1024.0f) + 1e-5f);

    float* op = out + (size_t)row * 1024 + lane * 16;
#pragma unroll
    for (int q = 0; q < 4; ++q) {
        f32x4 o4;
#pragma unroll
        for (int j = 0; j < 4; ++j) {
            const int e = q * 4 + j;
            o4[j] = tanhf(xs[e] * rsx + hs[e] * rsh);
        }
        ((f32x4*)op)[q] = o4;
    }
}

extern "C" void kernel_launch(void* const* d_in, const int* in_sizes, int n_in,
                              void* d_out, int out_size, void* d_ws, size_t ws_size,
                              hipStream_t stream)
{
    const float* input_ = (const float*)d_in[0];
    const float* hidden = (const float*)d_in[1];
    const float* Wi     = (const float*)d_in[2];
    const float* bi     = (const float*)d_in[3];
    const float* Wr     = (const float*)d_in[4];
    const float* br     = (const float*)d_in[5];
    float* out = (float*)d_out;

    char* ws = (char*)d_ws;
    float* bmax   = (float*)ws;
    float* scales = (float*)(ws + 2048);
    __bf16* Qi  = (__bf16*)(ws + 4096);
    __bf16* Qr  = (__bf16*)(ws + 4096 + (1u << 21));
    __bf16* Abf = (__bf16*)(ws + 4096 + (2u << 21));
    __bf16* Hbf = (__bf16*)(ws + 4096 + (2u << 21) + (1u << 23));
    __bf16* Xq  = (__bf16*)(ws + 4096 + (2u << 21) + (2u << 23));
    __bf16* Hq  = (__bf16*)(ws + 4096 + (2u << 21) + (3u << 23));

    prep1_k<<<2560, 256, 0, stream>>>(input_, hidden, Wi, Wr, bmax, Abf, Hbf);
    quant_k<<<512, 256, 0, stream>>>(Wi, Wr, bmax, scales, Qi, Qr);
    gemm_dual<<<512, 256, 0, stream>>>(Abf, Hbf, Qi, Qr, Xq, Hq);
    ln_tanh_k<<<1024, 256, 0, stream>>>(Xq, Hq, bi, br, scales, out);
}